// Round 7
// baseline (843.035 us; speedup 1.0000x reference)
//
#include <hip/hip_runtime.h>
#include <math.h>

// Problem constants (fixed shapes from setup_inputs)
#define Bn 32
#define TT 512
#define TM 2048
#define DD 512
#define MMp 80
#define NEGF (-1.0e9f)

// d_out layout: [h_expanded 32*2048*512][dur_loss 1][durations 32*512], all float32
constexpr size_t LOSS_OFF = (size_t)Bn * TM * DD;          // 33554432
constexpr size_t DUR_OFF  = LOSS_OFF + 1;                  // 33554433

// ---------------------------------------------------------------------------
// K0: build wTx[96][512]: rows 0..79 = w_proj^T, row 80 = b_proj, 81..95 = 0
// ---------------------------------------------------------------------------
__global__ __launch_bounds__(256) void k0_wtx(const float* __restrict__ w,
                                              const float* __restrict__ bias,
                                              float* __restrict__ wTx) {
    int m = blockIdx.x;
    for (int d = threadIdx.x; d < DD; d += 256) {
        float v = 0.f;
        if (m < 80) v = w[d * 80 + m];
        else if (m == 80) v = bias[d];
        wTx[m * DD + d] = v;
    }
}

// ---------------------------------------------------------------------------
// K1: hwX[b][m][i] = sum_d h_text[b][i][d] * wTx[m][d]   (m<96, row80 = h.b)
// ---------------------------------------------------------------------------
__global__ __launch_bounds__(256) void k1_hw(const float* __restrict__ h_text,
                                             const float* __restrict__ wTx,
                                             float* __restrict__ hwX) {
    int bid = blockIdx.x;
    int b = bid >> 3;
    int i0 = (bid & 7) * 64;
    int t = threadIdx.x;
    int tr = t & 15, tc = t >> 4;
    __shared__ __align__(16) float Asub[64 * 68];
    __shared__ __align__(16) float Bsub[96 * 68];
    float acc[4][6];
#pragma unroll
    for (int a = 0; a < 4; ++a)
#pragma unroll
        for (int c = 0; c < 6; ++c) acc[a][c] = 0.f;

    for (int d0 = 0; d0 < DD; d0 += 64) {
        __syncthreads();
#pragma unroll
        for (int p = 0; p < 4; ++p) {
            int lin = p * 256 + t;              // 0..1023
            int r = lin >> 4, dq = lin & 15;
            *(float4*)&Asub[r * 68 + dq * 4] =
                *(const float4*)&h_text[((size_t)(b * TT + i0 + r)) * DD + d0 + dq * 4];
        }
#pragma unroll
        for (int p = 0; p < 6; ++p) {
            int lin = p * 256 + t;              // 0..1535
            int cc = lin >> 4, dq = lin & 15;
            *(float4*)&Bsub[cc * 68 + dq * 4] =
                *(const float4*)&wTx[(size_t)cc * DD + d0 + dq * 4];
        }
        __syncthreads();
#pragma unroll
        for (int dd = 0; dd < 16; ++dd) {
            float4 a[4], bb[6];
#pragma unroll
            for (int ri = 0; ri < 4; ++ri)
                a[ri] = *(const float4*)&Asub[(tr * 4 + ri) * 68 + dd * 4];
#pragma unroll
            for (int ci = 0; ci < 6; ++ci)
                bb[ci] = *(const float4*)&Bsub[(tc * 6 + ci) * 68 + dd * 4];
#pragma unroll
            for (int ri = 0; ri < 4; ++ri)
#pragma unroll
                for (int ci = 0; ci < 6; ++ci) {
                    acc[ri][ci] += a[ri].x * bb[ci].x;
                    acc[ri][ci] += a[ri].y * bb[ci].y;
                    acc[ri][ci] += a[ri].z * bb[ci].z;
                    acc[ri][ci] += a[ri].w * bb[ci].w;
                }
        }
    }
#pragma unroll
    for (int ri = 0; ri < 4; ++ri)
#pragma unroll
        for (int ci = 0; ci < 6; ++ci)
            hwX[((size_t)b * 96 + tc * 6 + ci) * DD + i0 + tr * 4 + ri] = acc[ri][ci];
}

// ---------------------------------------------------------------------------
// K2: attn + masked log_softmax over text axis, written transposed:
//   logpT[b][j][i]
// ---------------------------------------------------------------------------
__global__ __launch_bounds__(256) void k2_attn(const float* __restrict__ hwX,
                                               const float* __restrict__ mel,
                                               const int* __restrict__ tlen,
                                               const int* __restrict__ mlen,
                                               float* __restrict__ logpT) {
    const int b = blockIdx.y;
    const int ml = mlen[b];
    const int j0 = blockIdx.x * 32;
    if (j0 >= ml) return;
    const int tl = tlen[b];
    const int tid = threadIdx.x;
    const int ig = tid >> 2;   // 64 i-groups, 8 rows each
    const int jg = tid & 3;    // 4 j-groups, 8 cols each

    __shared__ __align__(16) float hwS[16 * 512];
    __shared__ __align__(16) float melS[16 * 32];
    __shared__ float red[32 * 64];
    __shared__ float colmax[32];
    __shared__ float lsum[32];

    float acc[8][8];
#pragma unroll
    for (int a = 0; a < 8; ++a)
#pragma unroll
        for (int c = 0; c < 8; ++c) acc[a][c] = 0.f;

    for (int mc = 0; mc < 80; mc += 16) {
        __syncthreads();
#pragma unroll
        for (int p = 0; p < 8; ++p) {
            int lin = p * 256 + tid;            // 0..2047 float4s
            int mm = lin >> 7, iq = lin & 127;
            *(float4*)&hwS[mm * 512 + iq * 4] =
                *(const float4*)&hwX[((size_t)b * 96 + mc + mm) * DD + iq * 4];
        }
#pragma unroll
        for (int p = 0; p < 2; ++p) {
            int lin = p * 256 + tid;            // 0..511
            int mm = lin >> 5, jj = lin & 31;
            melS[lin] = mel[((size_t)b * 80 + mc + mm) * TM + j0 + jj];
        }
        __syncthreads();
#pragma unroll
        for (int mm = 0; mm < 16; ++mm) {
            float4 a0 = *(const float4*)&hwS[mm * 512 + ig * 8];
            float4 a1 = *(const float4*)&hwS[mm * 512 + ig * 8 + 4];
            float4 b0 = *(const float4*)&melS[mm * 32 + jg * 8];
            float4 b1 = *(const float4*)&melS[mm * 32 + jg * 8 + 4];
            float av[8] = {a0.x, a0.y, a0.z, a0.w, a1.x, a1.y, a1.z, a1.w};
            float bv[8] = {b0.x, b0.y, b0.z, b0.w, b1.x, b1.y, b1.z, b1.w};
#pragma unroll
            for (int ii = 0; ii < 8; ++ii)
#pragma unroll
                for (int jj = 0; jj < 8; ++jj) acc[ii][jj] += av[ii] * bv[jj];
        }
    }
    float4 h0 = *(const float4*)&hwX[((size_t)b * 96 + 80) * DD + ig * 8];
    float4 h1 = *(const float4*)&hwX[((size_t)b * 96 + 80) * DD + ig * 8 + 4];
    float hb[8] = {h0.x, h0.y, h0.z, h0.w, h1.x, h1.y, h1.z, h1.w};
#pragma unroll
    for (int ii = 0; ii < 8; ++ii) {
        bool valid = (ig * 8 + ii) < tl;
#pragma unroll
        for (int jj = 0; jj < 8; ++jj)
            acc[ii][jj] = valid ? (acc[ii][jj] + hb[ii]) : NEGF;
    }
    __syncthreads();
#pragma unroll
    for (int jj = 0; jj < 8; ++jj) {
        float m = acc[0][jj];
#pragma unroll
        for (int ii = 1; ii < 8; ++ii) m = fmaxf(m, acc[ii][jj]);
        red[(jg * 8 + jj) * 64 + ig] = m;
    }
    __syncthreads();
    if (tid < 32) {
        float m = red[tid * 64];
        for (int g = 1; g < 64; ++g) m = fmaxf(m, red[tid * 64 + g]);
        colmax[tid] = m;
    }
    __syncthreads();
#pragma unroll
    for (int jj = 0; jj < 8; ++jj) {
        float cm = colmax[jg * 8 + jj];
        float s = 0.f;
#pragma unroll
        for (int ii = 0; ii < 8; ++ii) s += expf(acc[ii][jj] - cm);
        red[(jg * 8 + jj) * 64 + ig] = s;
    }
    __syncthreads();
    if (tid < 32) {
        float s = 0.f;
        for (int g = 0; g < 64; ++g) s += red[tid * 64 + g];
        lsum[tid] = logf(s);
    }
    __syncthreads();
#pragma unroll
    for (int jj = 0; jj < 8; ++jj) {
        int j = j0 + jg * 8 + jj;
        if (j < ml) {
            float cm = colmax[jg * 8 + jj], ls = lsum[jg * 8 + jj];
            float o[8];
#pragma unroll
            for (int ii = 0; ii < 8; ++ii) {
                int i = ig * 8 + ii;
                o[ii] = (i < tl) ? ((acc[ii][jj] - cm) - ls) : NEGF;
            }
            float* dst = &logpT[((size_t)b * TM + j) * TT + ig * 8];
            *(float4*)dst = make_float4(o[0], o[1], o[2], o[3]);
            *(float4*)(dst + 4) = make_float4(o[4], o[5], o[6], o[7]);
        }
    }
}

// ---------------------------------------------------------------------------
// K3: MAS forward DP, r11: MULTI-PRODUCER wave-split DMA.
// Model closed by r4/r9/r10: per-DMA cost is ~265 cyc *per wave* regardless
// of wait structure (r4 drain-0: 263, r9 1-producer: 265, r10 counted
// vmcnt(32): 265) => global_load_lds does not pipeline deeply from a single
// wave. m97's GEMM shows the per-CU DMA path sustains ~56 cyc/DMA when the
// DMAs come from MANY waves. So: split the 32 DMAs/batch across 8 producer
// waves (4 each, draining concurrently under the consumer's compute).
//   wave 0   : consumer — r10's group-ahead LDS reader + DP (no vm ops of
//              its own except gwords stores)
//   waves 1-8: producers — each owns 2 columns (4 DMAs) of batch n+1
// One __syncthreads per batch; 2-slot 64KB ring; per-batch time ≈
// max(consumer ~1600, per-wave 4x265≈1060, per-CU 32x56≈1800) cyc.
// DP core / gwords layout / backtrack / scatter verbatim from r9/r10
// (hardware-verified, absmax 0). Lane l owns rows {4l..4l+3, 256+4l..+3};
// row 255->256 hand-off via DPP wave_ror:1 feeding wave_shr:1's lane-0 hole.
// Tail over-read (col 2048) lands in hwX slack: finite garbage, never
// flushed, never read by backtrack.
// ---------------------------------------------------------------------------
#define KVB 16      // columns per batch
#define NKB 128     // batches: columns 1..2048 (2047 real + 1 slack)
#define K3T 576     // 9 waves: 1 consumer + 8 producers

typedef float vf4 __attribute__((ext_vector_type(4)));

__device__ __forceinline__ void lds_dma16(const float* g, float* l) {
    __builtin_amdgcn_global_load_lds((const __attribute__((address_space(1))) void*)g,
                                     (__attribute__((address_space(3))) void*)l,
                                     16, 0, 0);
}

// lane l gets src from lane l-1; lane 0 keeps `old`'s lane-0 value.
__device__ __forceinline__ float dpp_shr1(float old, float src) {
    return __int_as_float(__builtin_amdgcn_update_dpp(
        __float_as_int(old), __float_as_int(src), 0x138, 0xF, 0xF, false));
}
// full rotate: lane l gets lane (l-1)&63; lane 0 gets lane 63.
__device__ __forceinline__ float dpp_ror1(float src) {
    return __int_as_float(__builtin_amdgcn_update_dpp(
        __float_as_int(src), __float_as_int(src), 0x13C, 0xF, 0xF, false));
}

__global__ __launch_bounds__(K3T, 1) void k3_dp(const float* __restrict__ logpT,
                                                const int* __restrict__ tlen,
                                                const int* __restrict__ mlen,
                                                unsigned* __restrict__ gwords,
                                                int* __restrict__ idxmap,
                                                float* __restrict__ dOut) {
    const int b = blockIdx.x;
    const int tid = threadIdx.x;
    const int wid = tid >> 6;
    const int lane = tid & 63;
    const int tl = tlen[b];
    const int ml = mlen[b];

    __shared__ __align__(16) float ring[2][KVB][512];   // 64 KB
    __shared__ int durs[TT];
    for (int idx = tid; idx < TT; idx += K3T) durs[idx] = 0;

    const float* colbase = logpT + (size_t)b * TM * TT;
    unsigned* gwb = gwords + (size_t)b * TT * 64;

    // consumer DP state (meaningful in wave 0 only)
    float qa[4], qb[4];
    unsigned accA[4], accB[4];
#pragma unroll
    for (int k = 0; k < 4; ++k) { qa[k] = NEGF; qb[k] = NEGF; accA[k] = 0u; accB[k] = 0u; }
    if (wid == 0 && lane == 0) qa[0] = colbase[0];     // logp[b][j=0][i=0]
    unsigned* gpA = gwb + (size_t)(4 * lane) * 64;
    unsigned* gpB = gwb + (size_t)(256 + 4 * lane) * 64;
    int woff = 0;
    int jj = 1;
    const int lane4 = lane * 4;

    // producer: wave w (1..8) owns columns c0 = (w-1)*2, c0+1 of each batch
    const int pc0 = (wid - 1) * 2;

#define DMA_2COLS(nb_, slot_) do {                                             \
        const int j0_ = 1 + (nb_) * KVB + pc0;                                 \
        const float* src_ = colbase + (size_t)j0_ * 512 + lane4;               \
        float* dst_ = &ring[slot_][pc0][0];                                    \
        lds_dma16(src_,             dst_);                                     \
        lds_dma16(src_ + 256,       dst_ + 256);                               \
        lds_dma16(src_ + 512,       dst_ + 512);                               \
        lds_dma16(src_ + 512 + 256, dst_ + 512 + 256);                         \
    } while (0)

#define COL1(la_, lb_) do {                                                    \
        float wrap_ = dpp_ror1(qa[3]);             /* lane0 <- row 255 */      \
        float nA0_ = dpp_shr1(NEGF, qa[3]);        /* lane0 -> NEGF (row 0) */ \
        float nB0_ = dpp_shr1(wrap_, qb[3]);       /* lane0 -> row 255 q */    \
        float nA_[4], nB_[4];                                                  \
        nA_[0] = nA0_; nB_[0] = nB0_;                                          \
        _Pragma("unroll")                                                      \
        for (int k_ = 1; k_ < 4; ++k_) { nA_[k_] = qa[k_ - 1]; nB_[k_] = qb[k_ - 1]; } \
        const unsigned m32_ = 1u << (jj & 31);                                 \
        _Pragma("unroll")                                                      \
        for (int k_ = 0; k_ < 4; ++k_) {                                       \
            if (nA_[k_] > qa[k_]) accA[k_] |= m32_;                            \
            qa[k_] = la_[k_] + fmaxf(qa[k_], nA_[k_]);                         \
            if (nB_[k_] > qb[k_]) accB[k_] |= m32_;                            \
            qb[k_] = lb_[k_] + fmaxf(qb[k_], nB_[k_]);                         \
        }                                                                      \
        if ((jj & 31) == 31) {                     /* word complete */         \
            _Pragma("unroll")                                                  \
            for (int k_ = 0; k_ < 4; ++k_) {                                   \
                gpA[k_ * 64 + woff] = accA[k_]; accA[k_] = 0u;                 \
                gpB[k_ * 64 + woff] = accB[k_]; accB[k_] = 0u;                 \
            }                                                                  \
            ++woff;                                                            \
        }                                                                      \
        ++jj;                                                                  \
    } while (0)

#define READG(slab_, c0_, ga_, gb_) do {                                       \
        _Pragma("unroll")                                                      \
        for (int p_ = 0; p_ < 4; ++p_) {                                       \
            ga_[p_] = *(const vf4*)&slab_[(c0_ + p_) * 512 + lane4];           \
            gb_[p_] = *(const vf4*)&slab_[(c0_ + p_) * 512 + 256 + lane4];     \
        }                                                                      \
    } while (0)

#define COMPG(ga_, gb_) do {                                                   \
        _Pragma("unroll")                                                      \
        for (int p_ = 0; p_ < 4; ++p_) COL1(ga_[p_], gb_[p_]);                 \
    } while (0)

    // prologue: producers fill slot 0 with batch 0
    if (wid > 0) DMA_2COLS(0, 0);
    __syncthreads();   // producers' vmcnt(0) drain (compiler-inserted)

    for (int n = 0; n < NKB; ++n) {
        if (wid == 0) {
            // ---- consumer: 16 DP columns from current slot ----
            const float* slab = &ring[n & 1][0][0];
            vf4 xA[4], xB[4], yA[4], yB[4];
            READG(slab, 0, xA, xB);
            READG(slab, 4, yA, yB);
            COMPG(xA, xB);
            READG(slab, 8, xA, xB);
            COMPG(yA, yB);
            READG(slab, 12, yA, yB);
            COMPG(xA, xB);
            COMPG(yA, yB);
        } else {
            // ---- producers: fill the other slot with batch n+1 ----
            if (n + 1 < NKB) DMA_2COLS(n + 1, (n + 1) & 1);
        }
        __syncthreads();
    }
#undef DMA_2COLS
#undef COL1
#undef READG
#undef COMPG

    __threadfence();
    __syncthreads();

    if (wid == 0) {
        // ---- wave-parallel backtrack: lane = word index within a row ----
        {
            int i = tl - 1;
            int j = ml - 1;
            unsigned r0, r1, r2, r3, r4, r5, r6, r7;   // 8-deep row shift register
            {
                int a0 = tl - 1, a1 = tl - 2, a2 = tl - 3, a3 = tl - 4;
                int a4 = tl - 5, a5 = tl - 6, a6 = tl - 7, a7 = tl - 8;
                a1 = a1 < 0 ? 0 : a1; a2 = a2 < 0 ? 0 : a2; a3 = a3 < 0 ? 0 : a3;
                a4 = a4 < 0 ? 0 : a4; a5 = a5 < 0 ? 0 : a5; a6 = a6 < 0 ? 0 : a6;
                a7 = a7 < 0 ? 0 : a7;
                r0 = gwb[a0 * 64 + lane]; r1 = gwb[a1 * 64 + lane];
                r2 = gwb[a2 * 64 + lane]; r3 = gwb[a3 * 64 + lane];
                r4 = gwb[a4 * 64 + lane]; r5 = gwb[a5 * 64 + lane];
                r6 = gwb[a6 * 64 + lane]; r7 = gwb[a7 * 64 + lane];
            }
            int nf = tl - 9;
            int guard = TT + 2;
            while (guard-- > 0) {
                unsigned w = r0;
                r0 = r1; r1 = r2; r2 = r3; r3 = r4; r4 = r5; r5 = r6; r6 = r7;
                {
                    int rf = (nf < 0) ? 0 : nf;
                    r7 = gwb[rf * 64 + lane];
                    --nf;
                }
                int jw = j >> 5, rr = j & 31;
                unsigned topmask = (rr == 31) ? 0xFFFFFFFFu : ((1u << (rr + 1)) - 1u);
                unsigned wm = (lane < jw) ? w : ((lane == jw) ? (w & topmask) : 0u);
                unsigned long long bal = __ballot(wm != 0u);
                if (bal == 0ull) {               // no transition: row i covers 0..j
                    if (lane == 0) durs[i] = j + 1;
                    break;
                }
                int hl = 63 - __clzll(bal);      // highest lane (word) with a bit
                unsigned whl = (unsigned)__builtin_amdgcn_readlane((int)wm, hl);
                int jp = (hl << 5) + (31 - __clz(whl));   // largest set bit <= j
                if (lane == 0) durs[i] = j - jp + 1;
                j = jp - 1;
                if (--i < 0) break;
            }
        }

        // ---- durations -> d_out; exclusive cumsum -> idxmap scatter fill ----
        // Scatter clamped to TM: DP corruption shows as absmax, never OOB.
        int d[8], pre[8];
        int run = 0;
#pragma unroll
        for (int k = 0; k < 8; ++k) { d[k] = durs[lane * 8 + k]; pre[k] = run; run += d[k]; }
        int v = run;
#pragma unroll
        for (int off = 1; off < 64; off <<= 1) {
            int n = __shfl_up(v, off);
            if (lane >= off) v += n;
        }
        int base = v - run;
#pragma unroll
        for (int k = 0; k < 8; ++k) {
            int i = lane * 8 + k;
            dOut[DUR_OFF + (size_t)b * TT + i] = (float)d[k];
            int st = base + pre[k];
            int en = st + d[k];
            if (en > TM) en = TM;
            if (st < 0) st = 0;
            for (int t2 = st; t2 < en; ++t2) idxmap[b * TM + t2] = i;
        }
    }
}

// ---------------------------------------------------------------------------
// K4: length-regulate expansion. One block per output row (b, j).
// Index clamped to [0,511]: any upstream DP corruption becomes a diagnosable
// absmax failure instead of an OOB read -> SIGABRT with no counters.
// ---------------------------------------------------------------------------
__global__ __launch_bounds__(128) void k4_expand(const float* __restrict__ h_text,
                                                 const int* __restrict__ idxmap,
                                                 const int* __restrict__ mlen,
                                                 float* __restrict__ dOut) {
    int bid = blockIdx.x;
    int b = bid >> 11;
    int j = bid & (TM - 1);
    int t = threadIdx.x;
    float4* orow = (float4*)dOut + (size_t)bid * 128;
    if (j < mlen[b]) {
        int i = idxmap[bid] & (TT - 1);
        const float4* hrow = (const float4*)h_text + ((size_t)(b * TT + i)) * 128;
        orow[t] = hrow[t];
    } else {
        orow[t] = make_float4(0.f, 0.f, 0.f, 0.f);
    }
}

// ---------------------------------------------------------------------------
// K5: masked sum-MSE duration loss
// ---------------------------------------------------------------------------
__global__ __launch_bounds__(256) void k5_loss(const float* __restrict__ pred,
                                               const int* __restrict__ tlen,
                                               float* __restrict__ dOut) {
    __shared__ float rs[256];
    __shared__ int rc[256];
    int t = threadIdx.x;
    float s = 0.f;
    int c = 0;
    for (int idx = t; idx < Bn * TT; idx += 256) {
        int b = idx >> 9, i = idx & 511;
        if (i < tlen[b]) {
            float dv = dOut[DUR_OFF + idx];
            float lg = logf(fmaxf(dv, 1.0f));
            float df = pred[idx] - lg;
            s += df * df;
            c += 1;
        }
    }
    rs[t] = s; rc[t] = c;
    __syncthreads();
    for (int off = 128; off > 0; off >>= 1) {
        if (t < off) { rs[t] += rs[t + off]; rc[t] += rc[t + off]; }
        __syncthreads();
    }
    if (t == 0) dOut[LOSS_OFF] = rs[0] / (float)rc[0];
}

// ---------------------------------------------------------------------------
extern "C" void kernel_launch(void* const* d_in, const int* in_sizes, int n_in,
                              void* d_out, int out_size, void* d_ws, size_t ws_size,
                              hipStream_t stream) {
    const float* h_text = (const float*)d_in[0];
    const float* mel    = (const float*)d_in[1];
    const int*   tlen   = (const int*)d_in[2];
    const int*   mlen   = (const int*)d_in[3];
    const float* w      = (const float*)d_in[4];
    const float* bias   = (const float*)d_in[5];
    const float* pred   = (const float*)d_in[6];
    float* out = (float*)d_out;

    // workspace carve-up (~138.5 MB)
    float*    logpT  = (float*)d_ws;                              // 32*2048*512 f32 (128 MB)
    float*    hwX    = logpT + (size_t)Bn * TM * TT;              // 32*96*512 f32 (also k3's over-read slack)
    float*    wTx    = hwX + (size_t)Bn * 96 * DD;                // 96*512 f32
    unsigned* gwords = (unsigned*)(wTx + 96 * DD);                // 32*512*64 u32 (4 MB)
    int*      idxmap = (int*)(gwords + (size_t)Bn * TT * 64);     // 32*2048 i32

    k0_wtx<<<dim3(96), dim3(256), 0, stream>>>(w, bias, wTx);
    k1_hw<<<dim3(256), dim3(256), 0, stream>>>(h_text, wTx, hwX);
    k2_attn<<<dim3(64, 32), dim3(256), 0, stream>>>(hwX, mel, tlen, mlen, logpT);
    k3_dp<<<dim3(32), dim3(K3T), 0, stream>>>(logpT, tlen, mlen, gwords, idxmap, out);
    k4_expand<<<dim3(Bn * TM), dim3(128), 0, stream>>>(h_text, idxmap, mlen, out);
    k5_loss<<<dim3(1), dim3(256), 0, stream>>>(pred, tlen, out);
}

// Round 8
// 727.591 us; speedup vs baseline: 1.1587x; 1.1587x over previous
//
#include <hip/hip_runtime.h>
#include <math.h>

// Problem constants (fixed shapes from setup_inputs)
#define Bn 32
#define TT 512
#define TM 2048
#define DD 512
#define MMp 80
#define NEGF (-1.0e9f)

// d_out layout: [h_expanded 32*2048*512][dur_loss 1][durations 32*512], all float32
constexpr size_t LOSS_OFF = (size_t)Bn * TM * DD;          // 33554432
constexpr size_t DUR_OFF  = LOSS_OFF + 1;                  // 33554433

// ---------------------------------------------------------------------------
// K0: build wTx[96][512]: rows 0..79 = w_proj^T, row 80 = b_proj, 81..95 = 0
// ---------------------------------------------------------------------------
__global__ __launch_bounds__(256) void k0_wtx(const float* __restrict__ w,
                                              const float* __restrict__ bias,
                                              float* __restrict__ wTx) {
    int m = blockIdx.x;
    for (int d = threadIdx.x; d < DD; d += 256) {
        float v = 0.f;
        if (m < 80) v = w[d * 80 + m];
        else if (m == 80) v = bias[d];
        wTx[m * DD + d] = v;
    }
}

// ---------------------------------------------------------------------------
// K1: hwX[b][m][i] = sum_d h_text[b][i][d] * wTx[m][d]   (m<96, row80 = h.b)
// ---------------------------------------------------------------------------
__global__ __launch_bounds__(256) void k1_hw(const float* __restrict__ h_text,
                                             const float* __restrict__ wTx,
                                             float* __restrict__ hwX) {
    int bid = blockIdx.x;
    int b = bid >> 3;
    int i0 = (bid & 7) * 64;
    int t = threadIdx.x;
    int tr = t & 15, tc = t >> 4;
    __shared__ __align__(16) float Asub[64 * 68];
    __shared__ __align__(16) float Bsub[96 * 68];
    float acc[4][6];
#pragma unroll
    for (int a = 0; a < 4; ++a)
#pragma unroll
        for (int c = 0; c < 6; ++c) acc[a][c] = 0.f;

    for (int d0 = 0; d0 < DD; d0 += 64) {
        __syncthreads();
#pragma unroll
        for (int p = 0; p < 4; ++p) {
            int lin = p * 256 + t;              // 0..1023
            int r = lin >> 4, dq = lin & 15;
            *(float4*)&Asub[r * 68 + dq * 4] =
                *(const float4*)&h_text[((size_t)(b * TT + i0 + r)) * DD + d0 + dq * 4];
        }
#pragma unroll
        for (int p = 0; p < 6; ++p) {
            int lin = p * 256 + t;              // 0..1535
            int cc = lin >> 4, dq = lin & 15;
            *(float4*)&Bsub[cc * 68 + dq * 4] =
                *(const float4*)&wTx[(size_t)cc * DD + d0 + dq * 4];
        }
        __syncthreads();
#pragma unroll
        for (int dd = 0; dd < 16; ++dd) {
            float4 a[4], bb[6];
#pragma unroll
            for (int ri = 0; ri < 4; ++ri)
                a[ri] = *(const float4*)&Asub[(tr * 4 + ri) * 68 + dd * 4];
#pragma unroll
            for (int ci = 0; ci < 6; ++ci)
                bb[ci] = *(const float4*)&Bsub[(tc * 6 + ci) * 68 + dd * 4];
#pragma unroll
            for (int ri = 0; ri < 4; ++ri)
#pragma unroll
                for (int ci = 0; ci < 6; ++ci) {
                    acc[ri][ci] += a[ri].x * bb[ci].x;
                    acc[ri][ci] += a[ri].y * bb[ci].y;
                    acc[ri][ci] += a[ri].z * bb[ci].z;
                    acc[ri][ci] += a[ri].w * bb[ci].w;
                }
        }
    }
#pragma unroll
    for (int ri = 0; ri < 4; ++ri)
#pragma unroll
        for (int ci = 0; ci < 6; ++ci)
            hwX[((size_t)b * 96 + tc * 6 + ci) * DD + i0 + tr * 4 + ri] = acc[ri][ci];
}

// ---------------------------------------------------------------------------
// K2: attn + masked log_softmax over text axis, written transposed:
//   logpT[b][j][i]
// ---------------------------------------------------------------------------
__global__ __launch_bounds__(256) void k2_attn(const float* __restrict__ hwX,
                                               const float* __restrict__ mel,
                                               const int* __restrict__ tlen,
                                               const int* __restrict__ mlen,
                                               float* __restrict__ logpT) {
    const int b = blockIdx.y;
    const int ml = mlen[b];
    const int j0 = blockIdx.x * 32;
    if (j0 >= ml) return;
    const int tl = tlen[b];
    const int tid = threadIdx.x;
    const int ig = tid >> 2;   // 64 i-groups, 8 rows each
    const int jg = tid & 3;    // 4 j-groups, 8 cols each

    __shared__ __align__(16) float hwS[16 * 512];
    __shared__ __align__(16) float melS[16 * 32];
    __shared__ float red[32 * 64];
    __shared__ float colmax[32];
    __shared__ float lsum[32];

    float acc[8][8];
#pragma unroll
    for (int a = 0; a < 8; ++a)
#pragma unroll
        for (int c = 0; c < 8; ++c) acc[a][c] = 0.f;

    for (int mc = 0; mc < 80; mc += 16) {
        __syncthreads();
#pragma unroll
        for (int p = 0; p < 8; ++p) {
            int lin = p * 256 + tid;            // 0..2047 float4s
            int mm = lin >> 7, iq = lin & 127;
            *(float4*)&hwS[mm * 512 + iq * 4] =
                *(const float4*)&hwX[((size_t)b * 96 + mc + mm) * DD + iq * 4];
        }
#pragma unroll
        for (int p = 0; p < 2; ++p) {
            int lin = p * 256 + tid;            // 0..511
            int mm = lin >> 5, jj = lin & 31;
            melS[lin] = mel[((size_t)b * 80 + mc + mm) * TM + j0 + jj];
        }
        __syncthreads();
#pragma unroll
        for (int mm = 0; mm < 16; ++mm) {
            float4 a0 = *(const float4*)&hwS[mm * 512 + ig * 8];
            float4 a1 = *(const float4*)&hwS[mm * 512 + ig * 8 + 4];
            float4 b0 = *(const float4*)&melS[mm * 32 + jg * 8];
            float4 b1 = *(const float4*)&melS[mm * 32 + jg * 8 + 4];
            float av[8] = {a0.x, a0.y, a0.z, a0.w, a1.x, a1.y, a1.z, a1.w};
            float bv[8] = {b0.x, b0.y, b0.z, b0.w, b1.x, b1.y, b1.z, b1.w};
#pragma unroll
            for (int ii = 0; ii < 8; ++ii)
#pragma unroll
                for (int jj = 0; jj < 8; ++jj) acc[ii][jj] += av[ii] * bv[jj];
        }
    }
    float4 h0 = *(const float4*)&hwX[((size_t)b * 96 + 80) * DD + ig * 8];
    float4 h1 = *(const float4*)&hwX[((size_t)b * 96 + 80) * DD + ig * 8 + 4];
    float hb[8] = {h0.x, h0.y, h0.z, h0.w, h1.x, h1.y, h1.z, h1.w};
#pragma unroll
    for (int ii = 0; ii < 8; ++ii) {
        bool valid = (ig * 8 + ii) < tl;
#pragma unroll
        for (int jj = 0; jj < 8; ++jj)
            acc[ii][jj] = valid ? (acc[ii][jj] + hb[ii]) : NEGF;
    }
    __syncthreads();
#pragma unroll
    for (int jj = 0; jj < 8; ++jj) {
        float m = acc[0][jj];
#pragma unroll
        for (int ii = 1; ii < 8; ++ii) m = fmaxf(m, acc[ii][jj]);
        red[(jg * 8 + jj) * 64 + ig] = m;
    }
    __syncthreads();
    if (tid < 32) {
        float m = red[tid * 64];
        for (int g = 1; g < 64; ++g) m = fmaxf(m, red[tid * 64 + g]);
        colmax[tid] = m;
    }
    __syncthreads();
#pragma unroll
    for (int jj = 0; jj < 8; ++jj) {
        float cm = colmax[jg * 8 + jj];
        float s = 0.f;
#pragma unroll
        for (int ii = 0; ii < 8; ++ii) s += expf(acc[ii][jj] - cm);
        red[(jg * 8 + jj) * 64 + ig] = s;
    }
    __syncthreads();
    if (tid < 32) {
        float s = 0.f;
        for (int g = 0; g < 64; ++g) s += red[tid * 64 + g];
        lsum[tid] = logf(s);
    }
    __syncthreads();
#pragma unroll
    for (int jj = 0; jj < 8; ++jj) {
        int j = j0 + jg * 8 + jj;
        if (j < ml) {
            float cm = colmax[jg * 8 + jj], ls = lsum[jg * 8 + jj];
            float o[8];
#pragma unroll
            for (int ii = 0; ii < 8; ++ii) {
                int i = ig * 8 + ii;
                o[ii] = (i < tl) ? ((acc[ii][jj] - cm) - ls) : NEGF;
            }
            float* dst = &logpT[((size_t)b * TM + j) * TT + ig * 8];
            *(float4*)dst = make_float4(o[0], o[1], o[2], o[3]);
            *(float4*)(dst + 4) = make_float4(o[4], o[5], o[6], o[7]);
        }
    }
}

// ---------------------------------------------------------------------------
// K3: MAS forward DP, r12: pin-anchored double buffer with PLAIN loads.
// Model closed over r4..r11: the LDS-DMA path runs at ~265 cyc/KB per CU
// regardless of wave count / wait structure (r4,r9,r10,r11 all ~450-470us)
// -> dead end. Plain loads are the fast path (r5/r8: 410 cyc/col = exactly
// one exposed latency per column, because load-sinking collapses prefetch).
// r12 keeps plain loads (compiler owns ALL waitcnt -> counted + store-aware
// + correct; the r6/r7 asm-copy hazard class is structurally impossible) and
// anchors the pipeline with PINS: asm volatile("" : "+v"(reg)) after the
// OTHER buffer's compute. A load cannot sink below its user, and volatile
// asms cannot reorder -> worst-case schedule still waits a full STEPS
// (~800 cyc) after issue. Exposed latency becomes per-batch, not per-column.
//   prologue: ISSUE(b0) ISSUE(b1) PIN(b0)
//   loop:     STEPS(b0) ISSUE(b0,n+2) PIN(b1) | STEPS(b1) ISSUE(b1,n+3) PIN(b0)
// 2x8-col reg buffers = 128 VGPR held live (VGPR_Count ~170-200 expected —
// that is the verification bit). DP core / gwords layout / backtrack /
// scatter verbatim from r8 (hardware-verified, absmax 0).
// Tail over-read (cols 2048..2064) lands in hwX slack: finite garbage,
// never flushed (word-64 bits), never read by backtrack.
// One wave per batch; lane l owns rows 8l..8l+7; DPP wave_shr:1 passes q[7].
// ---------------------------------------------------------------------------
#define BCOLS 8
#define NBATCH 256   // columns processed: 1..2048 (2047 real + 1 slack)

typedef float vf4 __attribute__((ext_vector_type(4)));

#define SB0() __builtin_amdgcn_sched_barrier(0)

// lane l gets src from lane l-1; lane 0 gets `old` (bound_ctrl=false).
__device__ __forceinline__ float dpp_shr1(float old, float src) {
    return __int_as_float(__builtin_amdgcn_update_dpp(
        __float_as_int(old), __float_as_int(src), 0x138, 0xF, 0xF, false));
}

__global__ __launch_bounds__(64, 1) void k3_dp(const float* __restrict__ logpT,
                                               const int* __restrict__ tlen,
                                               const int* __restrict__ mlen,
                                               unsigned* __restrict__ gwords,
                                               int* __restrict__ idxmap,
                                               float* __restrict__ dOut) {
    const int b = blockIdx.x;
    const int lane = threadIdx.x;
    const int tl = tlen[b];
    const int ml = mlen[b];
    __shared__ int durs[TT];
#pragma unroll
    for (int k = 0; k < 8; ++k) durs[lane * 8 + k] = 0;

    const float* colbase = logpT + (size_t)b * TM * TT;
    unsigned* gwb = gwords + (size_t)b * TT * 64;

    float q[8];
    unsigned accb[8];
#pragma unroll
    for (int k = 0; k < 8; ++k) { q[k] = NEGF; accb[k] = 0u; }
    if (lane == 0) q[0] = colbase[0];          // logp[b][j=0][i=0]

    unsigned* gp = gwb + lane * 8 * 64;        // flush cursor (word 0)
    int jj = 1;
    const float* lanebase = colbase + lane * 8;   // lane's 32B within a column

    // double-buffered register file: 2 batches x 8 cols x 8 floats = 128 VGPR
    vf4 ra0[BCOLS], rb0[BCOLS], ra1[BCOLS], rb1[BCOLS];

#define ISSUE(nb_, ra_, rb_) do {                                              \
        const float* g_ = lanebase + ((size_t)(1 + (nb_) * 8)) * 512;          \
        _Pragma("unroll")                                                      \
        for (int p_ = 0; p_ < BCOLS; ++p_) {                                   \
            ra_[p_] = *(const vf4*)(g_ + (size_t)p_ * 512);                    \
            rb_[p_] = *(const vf4*)(g_ + (size_t)p_ * 512 + 4);                \
        }                                                                      \
    } while (0)

// Pin: volatile asm reads+writes each buffered value. Loads cannot sink
// below their user; volatile asms cannot reorder or vanish. The compiler
// inserts a correctly-counted, store-aware s_waitcnt just before the pins.
#define PIN(ra_, rb_) do {                                                     \
        _Pragma("unroll")                                                      \
        for (int p_ = 0; p_ < BCOLS; ++p_) {                                   \
            asm volatile("" : "+v"(ra_[p_]));                                  \
            asm volatile("" : "+v"(rb_[p_]));                                  \
        }                                                                      \
    } while (0)

#define STEPS(ra_, rb_) do {                                                   \
        _Pragma("unroll")                                                      \
        for (int p_ = 0; p_ < BCOLS; ++p_) {                                   \
            float lp_[8] = {ra_[p_][0], ra_[p_][1], ra_[p_][2], ra_[p_][3],    \
                            rb_[p_][0], rb_[p_][1], rb_[p_][2], rb_[p_][3]};   \
            float nb_[8];                                                      \
            nb_[0] = dpp_shr1(NEGF, q[7]);                                     \
            _Pragma("unroll")                                                  \
            for (int k_ = 1; k_ < 8; ++k_) nb_[k_] = q[k_ - 1];                \
            const unsigned m32_ = 1u << (jj & 31);                             \
            _Pragma("unroll")                                                  \
            for (int k_ = 0; k_ < 8; ++k_) {                                   \
                if (nb_[k_] > q[k_]) accb[k_] |= m32_;                         \
                q[k_] = lp_[k_] + fmaxf(q[k_], nb_[k_]);                       \
            }                                                                  \
            if ((jj & 31) == 31) {             /* word complete (uniform) */   \
                _Pragma("unroll")                                              \
                for (int k_ = 0; k_ < 8; ++k_) {                               \
                    gp[k_ * 64] = accb[k_]; accb[k_] = 0u;                     \
                }                                                              \
                gp += 1;                                                       \
            }                                                                  \
            ++jj;                                                              \
        }                                                                      \
    } while (0)

    ISSUE(0, ra0, rb0);
    ISSUE(1, ra1, rb1);
    PIN(ra0, rb0);                              // prologue wait (once)
    for (int n = 0; n < NBATCH; n += 2) {
        SB0();
        STEPS(ra0, rb0);
        SB0();
        ISSUE(n + 2, ra0, rb0);                 // issue under STEPS(b1)
        SB0();
        PIN(ra1, rb1);                          // b1 issued a full iter ago
        SB0();
        STEPS(ra1, rb1);
        SB0();
        ISSUE(n + 3, ra1, rb1);                 // issue under next STEPS(b0)
        SB0();
        PIN(ra0, rb0);                          // window = STEPS(b1) ~800cyc
        SB0();
    }
#undef ISSUE
#undef PIN
#undef STEPS

    __threadfence();
    __syncthreads();

    // ---- wave-parallel backtrack: lane = word index within a row ----
    {
        int i = tl - 1;
        int j = ml - 1;
        unsigned r0, r1, r2, r3, r4, r5, r6, r7;   // 8-deep row shift register
        {
            int a0 = tl - 1, a1 = tl - 2, a2 = tl - 3, a3 = tl - 4;
            int a4 = tl - 5, a5 = tl - 6, a6 = tl - 7, a7 = tl - 8;
            a1 = a1 < 0 ? 0 : a1; a2 = a2 < 0 ? 0 : a2; a3 = a3 < 0 ? 0 : a3;
            a4 = a4 < 0 ? 0 : a4; a5 = a5 < 0 ? 0 : a5; a6 = a6 < 0 ? 0 : a6;
            a7 = a7 < 0 ? 0 : a7;
            r0 = gwb[a0 * 64 + lane]; r1 = gwb[a1 * 64 + lane];
            r2 = gwb[a2 * 64 + lane]; r3 = gwb[a3 * 64 + lane];
            r4 = gwb[a4 * 64 + lane]; r5 = gwb[a5 * 64 + lane];
            r6 = gwb[a6 * 64 + lane]; r7 = gwb[a7 * 64 + lane];
        }
        int nf = tl - 9;
        int guard = TT + 2;
        while (guard-- > 0) {
            unsigned w = r0;
            r0 = r1; r1 = r2; r2 = r3; r3 = r4; r4 = r5; r5 = r6; r6 = r7;
            {
                int rf = (nf < 0) ? 0 : nf;
                r7 = gwb[rf * 64 + lane];
                --nf;
            }
            int jw = j >> 5, rr = j & 31;
            unsigned topmask = (rr == 31) ? 0xFFFFFFFFu : ((1u << (rr + 1)) - 1u);
            unsigned wm = (lane < jw) ? w : ((lane == jw) ? (w & topmask) : 0u);
            unsigned long long bal = __ballot(wm != 0u);
            if (bal == 0ull) {                 // no transition: row i covers 0..j
                if (lane == 0) durs[i] = j + 1;
                break;
            }
            int hl = 63 - __clzll(bal);        // highest lane (word) with a bit
            unsigned whl = (unsigned)__builtin_amdgcn_readlane((int)wm, hl);
            int jp = (hl << 5) + (31 - __clz(whl));   // largest set bit <= j
            if (lane == 0) durs[i] = j - jp + 1;
            j = jp - 1;
            if (--i < 0) break;
        }
    }
    __syncthreads();

    // ---- durations -> d_out; exclusive cumsum -> idxmap scatter fill ----
    // Scatter clamped to TM: DP corruption shows as absmax, never OOB/abort.
    int d[8], pre[8];
    int run = 0;
#pragma unroll
    for (int k = 0; k < 8; ++k) { d[k] = durs[lane * 8 + k]; pre[k] = run; run += d[k]; }
    int v = run;
#pragma unroll
    for (int off = 1; off < 64; off <<= 1) {
        int n = __shfl_up(v, off);
        if (lane >= off) v += n;
    }
    int base = v - run;
#pragma unroll
    for (int k = 0; k < 8; ++k) {
        int i = lane * 8 + k;
        dOut[DUR_OFF + (size_t)b * TT + i] = (float)d[k];
        int st = base + pre[k];
        int en = st + d[k];
        if (en > TM) en = TM;
        if (st < 0) st = 0;
        for (int t2 = st; t2 < en; ++t2) idxmap[b * TM + t2] = i;
    }
}

// ---------------------------------------------------------------------------
// K4: length-regulate expansion. One block per output row (b, j).
// Index clamped to [0,511]: any upstream DP corruption becomes a diagnosable
// absmax failure instead of an OOB read -> SIGABRT with no counters.
// ---------------------------------------------------------------------------
__global__ __launch_bounds__(128) void k4_expand(const float* __restrict__ h_text,
                                                 const int* __restrict__ idxmap,
                                                 const int* __restrict__ mlen,
                                                 float* __restrict__ dOut) {
    int bid = blockIdx.x;
    int b = bid >> 11;
    int j = bid & (TM - 1);
    int t = threadIdx.x;
    float4* orow = (float4*)dOut + (size_t)bid * 128;
    if (j < mlen[b]) {
        int i = idxmap[bid] & (TT - 1);
        const float4* hrow = (const float4*)h_text + ((size_t)(b * TT + i)) * 128;
        orow[t] = hrow[t];
    } else {
        orow[t] = make_float4(0.f, 0.f, 0.f, 0.f);
    }
}

// ---------------------------------------------------------------------------
// K5: masked sum-MSE duration loss
// ---------------------------------------------------------------------------
__global__ __launch_bounds__(256) void k5_loss(const float* __restrict__ pred,
                                               const int* __restrict__ tlen,
                                               float* __restrict__ dOut) {
    __shared__ float rs[256];
    __shared__ int rc[256];
    int t = threadIdx.x;
    float s = 0.f;
    int c = 0;
    for (int idx = t; idx < Bn * TT; idx += 256) {
        int b = idx >> 9, i = idx & 511;
        if (i < tlen[b]) {
            float dv = dOut[DUR_OFF + idx];
            float lg = logf(fmaxf(dv, 1.0f));
            float df = pred[idx] - lg;
            s += df * df;
            c += 1;
        }
    }
    rs[t] = s; rc[t] = c;
    __syncthreads();
    for (int off = 128; off > 0; off >>= 1) {
        if (t < off) { rs[t] += rs[t + off]; rc[t] += rc[t + off]; }
        __syncthreads();
    }
    if (t == 0) dOut[LOSS_OFF] = rs[0] / (float)rc[0];
}

// ---------------------------------------------------------------------------
extern "C" void kernel_launch(void* const* d_in, const int* in_sizes, int n_in,
                              void* d_out, int out_size, void* d_ws, size_t ws_size,
                              hipStream_t stream) {
    const float* h_text = (const float*)d_in[0];
    const float* mel    = (const float*)d_in[1];
    const int*   tlen   = (const int*)d_in[2];
    const int*   mlen   = (const int*)d_in[3];
    const float* w      = (const float*)d_in[4];
    const float* bias   = (const float*)d_in[5];
    const float* pred   = (const float*)d_in[6];
    float* out = (float*)d_out;

    // workspace carve-up (~138.5 MB)
    float*    logpT  = (float*)d_ws;                              // 32*2048*512 f32 (128 MB)
    float*    hwX    = logpT + (size_t)Bn * TM * TT;              // 32*96*512 f32 (also k3's over-read slack)
    float*    wTx    = hwX + (size_t)Bn * 96 * DD;                // 96*512 f32
    unsigned* gwords = (unsigned*)(wTx + 96 * DD);                // 32*512*64 u32 (4 MB)
    int*      idxmap = (int*)(gwords + (size_t)Bn * TT * 64);     // 32*2048 i32

    k0_wtx<<<dim3(96), dim3(256), 0, stream>>>(w, bias, wTx);
    k1_hw<<<dim3(256), dim3(256), 0, stream>>>(h_text, wTx, hwX);
    k2_attn<<<dim3(64, 32), dim3(256), 0, stream>>>(hwX, mel, tlen, mlen, logpT);
    k3_dp<<<dim3(32), dim3(64), 0, stream>>>(logpT, tlen, mlen, gwords, idxmap, out);
    k4_expand<<<dim3(Bn * TM), dim3(128), 0, stream>>>(h_text, idxmap, mlen, out);
    k5_loss<<<dim3(1), dim3(256), 0, stream>>>(pred, tlen, out);
}